// Round 1
// baseline (222.765 us; speedup 1.0000x reference)
//
#include <hip/hip_runtime.h>
#include <math.h>

#define B_SIZE 8192
#define NVERT 778
#define NP 135
#define NEC 416
#define KS16 16

// ---- workspace layout (floats) ----
// Round 16 restructure: PP partial buffer eliminated (GEMM blocks atomicAdd
// straight into P2/C0/C1). Max ws use = AT end = 2,816,272 floats = 11.27 MB,
// identical to the previous minimum requirement (AT was always needed).
#define OFF_JK    0         // 48
#define OFF_C1    64        // 336  (21 x 16)
#define OFF_C0    400       // 1008 (21 x 48)
#define OFF_P2    1408      // 21*135*48 = 136080
#define OFF_PFT   137488    // 135 x 8192
#define OFF_AT    1243408   // 192 x 8192
#define ZERO_N    137424    // floats to zero: [OFF_C1, OFF_P2+136080)

__device__ inline void quat2mat_dev(float qw, float qx, float qy, float qz, float* R) {
  float n = sqrtf(qw*qw + qx*qx + qy*qy + qz*qz);
  float w = qw/n, x = qx/n, y = qy/n, z = qz/n;
  float w2=w*w, x2=x*x, y2=y*y, z2=z*z;
  float wx=w*x, wy=w*y, wz=w*z, xy=x*y, xz=x*z, yz=y*z;
  R[0]=w2+x2-y2-z2; R[1]=2.f*xy-2.f*wz; R[2]=2.f*wy+2.f*xz;
  R[3]=2.f*wz+2.f*xy; R[4]=w2-x2+y2-z2; R[5]=2.f*yz-2.f*wx;
  R[6]=2.f*xz-2.f*wy; R[7]=2.f*wx+2.f*yz; R[8]=w2-x2-y2+z2;
}

__device__ inline void rodrigues_dev(float tx, float ty, float tz, float* R) {
  float ax = tx + 1e-8f, ay = ty + 1e-8f, az = tz + 1e-8f;
  float angle = sqrtf(ax*ax + ay*ay + az*az);
  float nx = tx/angle, ny = ty/angle, nz = tz/angle;
  float half = 0.5f*angle;
  float cw = cosf(half), sw = sinf(half);
  quat2mat_dev(cw, sw*nx, sw*ny, sw*nz, R);
}

// pose_unit: UNCHANGED from the proven kernel.
__device__ inline void pose_unit(const float* __restrict__ theta,
                                 const float* __restrict__ delta_quat,
                                 const float* __restrict__ init_quat,
                                 float* __restrict__ ws,
                                 const float* jk, const float* rel,
                                 int bb, int u, int lane) {
  int b = bb*256 + lane;
  float* pfT = ws + OFF_PFT;
  float* AT  = ws + OFF_AT;
  float w1=delta_quat[b*4+0], x1=delta_quat[b*4+1], y1=delta_quat[b*4+2], z1=delta_quat[b*4+3];
  float w2=init_quat[0], x2=init_quat[1], y2=init_quat[2], z2=init_quat[3];
  float qw = w1*w2 - x1*x2 - y1*y2 - z1*z2;
  float qx = w1*x2 + x1*w2 + y1*z2 - z1*y2;
  float qy = w1*y2 - x1*z2 + y1*w2 + z1*x2;
  float qz = w1*z2 + x1*y2 - y1*x2 + z1*w2;
  float G[12];
  quat2mat_dev(qw, qx, qy, qz, G);
  G[9] = rel[0]; G[10] = rel[1]; G[11] = rel[2];
  if (u == 5) {
    #pragma unroll
    for (int c = 0; c < 3; ++c) {
      float g0 = G[c*3+0], g1 = G[c*3+1], g2 = G[c*3+2];
      AT[(size_t)(c*4+0)*B_SIZE + b] = g0;
      AT[(size_t)(c*4+1)*B_SIZE + b] = g1;
      AT[(size_t)(c*4+2)*B_SIZE + b] = g2;
      AT[(size_t)(c*4+3)*B_SIZE + b] = G[9+c] - (g0*jk[0] + g1*jk[1] + g2*jk[2]);
    }
    return;
  }
  #pragma unroll
  for (int mstep = 0; mstep < 3; ++mstep) {
    int j = 3*u + 1 + mstep;
    int i = j - 1;
    float R[9];
    rodrigues_dev(theta[b*45+3*i+0], theta[b*45+3*i+1], theta[b*45+3*i+2], R);
    pfT[(size_t)(9*i+0)*B_SIZE + b] = R[0]-1.f;
    pfT[(size_t)(9*i+1)*B_SIZE + b] = R[1];
    pfT[(size_t)(9*i+2)*B_SIZE + b] = R[2];
    pfT[(size_t)(9*i+3)*B_SIZE + b] = R[3];
    pfT[(size_t)(9*i+4)*B_SIZE + b] = R[4]-1.f;
    pfT[(size_t)(9*i+5)*B_SIZE + b] = R[5];
    pfT[(size_t)(9*i+6)*B_SIZE + b] = R[6];
    pfT[(size_t)(9*i+7)*B_SIZE + b] = R[7];
    pfT[(size_t)(9*i+8)*B_SIZE + b] = R[8]-1.f;
    float nG[12];
    const float* rj = rel + j*3;
    #pragma unroll
    for (int r3 = 0; r3 < 3; ++r3) {
      float a0 = G[r3*3+0], a1 = G[r3*3+1], a2 = G[r3*3+2];
      nG[r3*3+0] = a0*R[0] + a1*R[3] + a2*R[6];
      nG[r3*3+1] = a0*R[1] + a1*R[4] + a2*R[7];
      nG[r3*3+2] = a0*R[2] + a1*R[5] + a2*R[8];
      nG[9+r3]   = G[9+r3] + a0*rj[0] + a1*rj[1] + a2*rj[2];
    }
    #pragma unroll
    for (int k = 0; k < 12; ++k) G[k] = nG[k];
    const float* jkj = jk + j*3;
    #pragma unroll
    for (int c = 0; c < 3; ++c) {
      float g0 = G[c*3+0], g1 = G[c*3+1], g2 = G[c*3+2];
      AT[(size_t)(j*12 + c*4+0)*B_SIZE + b] = g0;
      AT[(size_t)(j*12 + c*4+1)*B_SIZE + b] = g1;
      AT[(size_t)(j*12 + c*4+2)*B_SIZE + b] = g2;
      AT[(size_t)(j*12 + c*4+3)*B_SIZE + b] = G[9+c] - (g0*jkj[0] + g1*jkj[1] + g2*jkj[2]);
    }
  }
}

// Dispatch 1: blocks 0..536 zero C1/C0/P2 (atomic accumulation targets);
// blocks 537..552 compute Jk (old kA blocks 416..431, verbatim).
__global__ __launch_bounds__(256) void kZJ(const float* __restrict__ J_regressor,
                                           const float* __restrict__ user_shape,
                                           const float* __restrict__ v_template,
                                           const float* __restrict__ shapedirs,
                                           float* __restrict__ ws) {
  int bid = blockIdx.x;
  int tid = threadIdx.x;
  if (bid < 537) {
    int idx = bid*256 + tid;
    if (idx < ZERO_N) ws[OFF_C1 + idx] = 0.f;
    return;
  }
  int j = bid - 537;
  __shared__ float red[3*256];
  __shared__ float ush[10];
  if (tid < 10) ush[tid] = user_shape[tid];
  __syncthreads();
  float p0 = 0.f, p1 = 0.f, p2 = 0.f;
  for (int v = tid; v < NVERT; v += 256) {
    float jr = J_regressor[v*21 + j];
    #pragma unroll
    for (int c = 0; c < 3; ++c) {
      int e = 3*v + c;
      float t = v_template[e];
      #pragma unroll
      for (int s = 0; s < 10; ++s) t += ush[s]*shapedirs[s*2334 + e];
      float val = jr * t;
      if (c == 0) p0 += val; else if (c == 1) p1 += val; else p2 += val;
    }
  }
  red[0*256+tid] = p0; red[1*256+tid] = p1; red[2*256+tid] = p2;
  __syncthreads();
  for (int s = 128; s > 0; s >>= 1) {
    if (tid < s) {
      red[0*256+tid] += red[0*256+tid+s];
      red[1*256+tid] += red[1*256+tid+s];
      red[2*256+tid] += red[2*256+tid+s];
    }
    __syncthreads();
  }
  if (tid < 3) ws[OFF_JK + j*3 + tid] = red[tid*256];
}

// Dispatch 2: blocks 0..415 = GEMM chunk blocks (identical compute to proven kA,
// epilogue changed from float4 stores to PP -> routed atomicAdd into P2/C0/C1,
// eliminating the 8.9 MB PP round-trip and the 137-block reduce phase).
// Blocks 416..607 = pose units (identical pose_unit, reads Jk from dispatch 1),
// now co-scheduled with the GEMM blocks instead of serialized behind them.
__global__ __launch_bounds__(256) void kAP(const float* __restrict__ theta,
                                           const float* __restrict__ delta_quat,
                                           const float* __restrict__ init_quat,
                                           const float* __restrict__ J_regressor,
                                           const float* __restrict__ weights,
                                           const float* __restrict__ posedirs,
                                           const float* __restrict__ user_shape,
                                           const float* __restrict__ v_template,
                                           const float* __restrict__ shapedirs,
                                           float* __restrict__ ws) {
  int bid = blockIdx.x;
  int tid = threadIdx.x;

  if (bid >= 416) {
    // pose path (same bb/u swizzle as proven kRk4: 416 % 8 == 0 keeps XCD spread)
    __shared__ float jk[48], rel[48];
    if (tid < 48) {
      float v = ws[OFF_JK + tid];
      jk[tid] = v;
      int j = tid/3, c = tid - j*3;
      float r;
      if (j == 0) r = v;
      else {
        int par = (((j-1) % 3) == 0) ? 0 : (j-1);
        r = v - ws[OFF_JK + par*3 + c];
      }
      rel[tid] = r;
    }
    __syncthreads();
    int q = bid - 416;
    int s = q & 7;
    int t = q >> 3;
    int bb = s + 8*(t & 3);
    int u  = t >> 2;
    pose_unit(theta, delta_quat, init_quat, ws, jk, rel, bb, u, tid);
    return;
  }

  __shared__ float sJR[49*21];
  __shared__ float sW [49*16];
  __shared__ float sB [64*16];
  __shared__ float ush[10];
  if (tid < 10) ush[tid] = user_shape[tid];
  int ng = bid % 26;
  int ks = bid / 26;
  int vbeg = ks*49;
  int kt = min(NVERT - vbeg, 49);
  __syncthreads();
  for (int idx = tid; idx < kt*21; idx += 256) sJR[idx] = J_regressor[vbeg*21 + idx];
  for (int idx = tid; idx < kt*16; idx += 256) sW[idx]  = weights[vbeg*16 + idx];
  for (int idx = tid; idx < 16*64; idx += 256) {
    int s = idx >> 6, iv = idx & 63;
    if (iv < kt) {
      int ec = ng*16 + s;
      float val;
      if (ec > 408) val = 0.f;
      else if (ec == 408) val = 1.f;
      else {
        int c = ec / 136, pp = ec - c*136;
        int e = 3*(vbeg+iv) + c;
        if (pp == 135) {
          float t = v_template[e];
          #pragma unroll
          for (int s0 = 0; s0 < 10; ++s0) t += ush[s0]*shapedirs[s0*2334 + e];
          val = t;
        } else {
          val = posedirs[pp*2334 + e];
        }
      }
      sB[iv*16 + s] = val;
    }
  }
  __syncthreads();
  if (tid < 168) {
    int cg2 = (tid < 84) ? 0 : 1;
    int r4  = (tid < 84) ? tid : tid - 84;
    int q2 = 4*r4;
    int j2b = q2 >> 4;
    int jb  = q2 & 15;
    (void)j2b;
    float acc[4][8];
    #pragma unroll
    for (int r = 0; r < 4; ++r)
      #pragma unroll
      for (int s = 0; s < 8; ++s) acc[r][s] = 0.f;
    for (int i = 0; i < kt; ++i) {
      float jr = sJR[i*21 + (q2 >> 4)];
      float4 w4 = *(const float4*)&sW[i*16 + jb];
      float4 b0 = *(const float4*)&sB[i*16 + cg2*8];
      float4 b1 = *(const float4*)&sB[i*16 + cg2*8 + 4];
      float wv[4] = {w4.x, w4.y, w4.z, w4.w};
      #pragma unroll
      for (int r = 0; r < 4; ++r) {
        float s2 = jr * wv[r];
        acc[r][0] += s2*b0.x; acc[r][1] += s2*b0.y;
        acc[r][2] += s2*b0.z; acc[r][3] += s2*b0.w;
        acc[r][4] += s2*b1.x; acc[r][5] += s2*b1.y;
        acc[r][6] += s2*b1.z; acc[r][7] += s2*b1.w;
      }
    }
    // routed atomic accumulation (replaces PP store + kr_task reduce):
    // element (ec, e=q2+r): jj2=e>>4, jj=e&15;
    //   ec<408: c=ec/136, pp=ec%136; pp<135 -> P2, pp==135 -> C0; ec==408 -> C1.
    #pragma unroll
    for (int s = 0; s < 8; ++s) {
      int ec = ng*16 + cg2*8 + s;
      if (ec > 408) continue;
      #pragma unroll
      for (int r = 0; r < 4; ++r) {
        int e = q2 + r;
        int jj2 = e >> 4, jj = e & 15;
        float val = acc[r][s];
        if (ec == 408) {
          atomicAdd(&ws[OFF_C1 + jj2*16 + jj], val);
        } else {
          int c = ec / 136, pp = ec - c*136;
          if (pp < 135) atomicAdd(&ws[OFF_P2 + (size_t)(jj2*135 + pp)*48 + jj*3 + c], val);
          else          atomicAdd(&ws[OFF_C0 + jj2*48 + jj*3 + c], val);
        }
      }
    }
  }
}

// k5: EXACT proven configuration (46-47 µs, FETCH 10.3 MB): 672 blocks x 256,
// XCD-swizzled, P2 via LDS-laundered VMEM path (in-order vmcnt -> pipelined
// float4 loads). UNTOUCHED this round — it is the control.
__global__ __launch_bounds__(256) void k5_main(const float* __restrict__ init_trans,
                                               const float* __restrict__ ws,
                                               float* __restrict__ out) {
  __shared__ int s_voff[1];
  int g = blockIdx.x;
  int xcd = g & 7, k = g >> 3;
  int br  = ((k & 3) << 3) | xcd;
  int j2  = k >> 2;
  int tid = threadIdx.x;
  int b   = br*256 + tid;

  if (tid == 0) s_voff[0] = j2*135*12;
  __syncthreads();
  int voff = s_voff[0];            // divergent in compiler's view -> VMEM addressing

  float4 acc[12];
  const float4* c04 = (const float4*)(ws + OFF_C0 + j2*48);
  #pragma unroll
  for (int i = 0; i < 12; ++i) acc[i] = c04[i];

  const float* pfT = ws + OFF_PFT;
  const float4* P24 = (const float4*)(ws + OFF_P2) + voff;
  #pragma unroll 3
  for (int p = 0; p < NP; ++p) {
    float pf = pfT[(size_t)p*B_SIZE + b];
    const float4* Pr = P24 + p*12;
    #pragma unroll
    for (int i = 0; i < 12; ++i) {
      float4 pv = Pr[i];
      acc[i].x += pf*pv.x; acc[i].y += pf*pv.y;
      acc[i].z += pf*pv.z; acc[i].w += pf*pv.w;
    }
  }

  float m[48];
  #pragma unroll
  for (int i = 0; i < 12; ++i) {
    m[4*i+0] = acc[i].x; m[4*i+1] = acc[i].y;
    m[4*i+2] = acc[i].z; m[4*i+3] = acc[i].w;
  }

  const float* AT  = ws + OFF_AT;
  const float* c1p = ws + OFF_C1 + j2*16;
  float o0 = 0.f, o1 = 0.f, o2 = 0.f;
  #pragma unroll
  for (int j = 0; j < 16; ++j) {
    float c1 = c1p[j];
    float m0 = m[3*j+0], m1 = m[3*j+1], m2 = m[3*j+2];
    #pragma unroll
    for (int k2 = 0; k2 < 3; ++k2) {
      float a0 = AT[(size_t)(j*12 + k2*4+0)*B_SIZE + b];
      float a1 = AT[(size_t)(j*12 + k2*4+1)*B_SIZE + b];
      float a2 = AT[(size_t)(j*12 + k2*4+2)*B_SIZE + b];
      float a3 = AT[(size_t)(j*12 + k2*4+3)*B_SIZE + b];
      float r = a0*m0 + a1*m1 + a2*m2 + a3*c1;
      if (k2 == 0) o0 += r; else if (k2 == 1) o1 += r; else o2 += r;
    }
  }
  size_t ob = ((size_t)b*21 + j2)*3;
  out[ob+0] = o0 + init_trans[b*3+0];
  out[ob+1] = o1 + init_trans[b*3+1];
  out[ob+2] = o2 + init_trans[b*3+2];
}

extern "C" void kernel_launch(void* const* d_in, const int* in_sizes, int n_in,
                              void* d_out, int out_size, void* d_ws, size_t ws_size,
                              hipStream_t stream) {
  const float* theta       = (const float*)d_in[0];
  const float* delta_quat  = (const float*)d_in[1];
  const float* user_shape  = (const float*)d_in[2];
  const float* init_quat   = (const float*)d_in[3];
  const float* init_trans  = (const float*)d_in[4];
  const float* v_template  = (const float*)d_in[5];
  const float* shapedirs   = (const float*)d_in[6];
  const float* J_regressor = (const float*)d_in[7];
  const float* posedirs    = (const float*)d_in[8];
  const float* weights     = (const float*)d_in[9];
  float* out = (float*)d_out;
  float* ws  = (float*)d_ws;

  // 3 dispatches: zero+Jk -> GEMM(atomic)+pose -> output.
  kZJ<<<553, 256, 0, stream>>>(J_regressor, user_shape, v_template, shapedirs, ws);
  kAP<<<608, 256, 0, stream>>>(theta, delta_quat, init_quat,
                               J_regressor, weights, posedirs,
                               user_shape, v_template, shapedirs, ws);
  k5_main<<<672, 256, 0, stream>>>(init_trans, ws, out);
}